// Round 1
// baseline (1172.097 us; speedup 1.0000x reference)
//
#include <hip/hip_runtime.h>
#include <float.h>
#include <math.h>

#define NROWS 65536
#define DIM 256
#define NCODES 2048

// ws layout:
// [0, 8192)     : usage  int[2048]
// [8192, 8196)  : commitment accumulator float
// [8208, 16400) : cbsq   float[2048]

// -------- codebook squared norms: one wave per code --------
__global__ void cbsq_kernel(const float* __restrict__ cb, float* __restrict__ cbsq) {
    int wid  = (blockIdx.x * blockDim.x + threadIdx.x) >> 6;   // 0..2047
    int lane = threadIdx.x & 63;
    const float4* c4 = (const float4*)cb;
    float4 v = c4[wid * 64 + lane];                            // 64 lanes * 4 = 256 elems
    float s = v.x * v.x + v.y * v.y + v.z * v.z + v.w * v.w;
    #pragma unroll
    for (int m = 32; m >= 1; m >>= 1) s += __shfl_xor(s, m, 64);
    if (lane == 0) cbsq[wid] = s;
}

// -------- distance argmin: block = 128 rows x all 2048 codes --------
// 512 blocks x 512 threads. Thread tile 4 rows x 8 codes.
// rows:  rg = t/16 (0..31) -> rows rg*4+i ; codes: cg = t%16 -> codes cg*8+j (per 128-chunk)
__global__ __launch_bounds__(512, 4)
void argmin_kernel(const float* __restrict__ z, const float* __restrict__ cb,
                   const float* __restrict__ cbsq, float* __restrict__ idx_out) {
    __shared__ float4 zs[128 * 16];   // 128 rows x 16 float4 (K-chunk of 64), swizzled
    __shared__ float4 ws[128 * 16];   // 128 codes x 16 float4, swizzled

    const int t    = threadIdx.x;
    const int rg   = t >> 4;          // 0..31
    const int cg   = t & 15;          // 0..15
    const int row0 = blockIdx.x * 128;
    const int tkk  = t & 15;          // staging: f4 index within K-chunk
    const int trow = t >> 4;          // staging: row/code base

    const float4* zg  = (const float4*)z;
    const float4* cbg = (const float4*)cb;

    float bd[4];
    int   bi[4];
    #pragma unroll
    for (int i = 0; i < 4; i++) { bd[i] = FLT_MAX; bi[i] = 0; }

    for (int chunk = 0; chunk < 16; chunk++) {
        const int code0 = chunk * 128;

        float acc[4][8];
        #pragma unroll
        for (int i = 0; i < 4; i++)
            #pragma unroll
            for (int j = 0; j < 8; j++) acc[i][j] = 0.0f;

        for (int kc = 0; kc < 4; kc++) {
            __syncthreads();   // protect LDS from previous iteration's readers
            // stage z tile: rows row0..row0+127, k in [kc*64, kc*64+64)
            #pragma unroll
            for (int it = 0; it < 4; it++) {
                int r = trow + 32 * it;
                zs[r * 16 + (tkk ^ ((r >> 2) & 15))] =
                    zg[(size_t)(row0 + r) * 64 + kc * 16 + tkk];
            }
            // stage w tile: codes code0..code0+127
            #pragma unroll
            for (int it = 0; it < 4; it++) {
                int c = trow + 32 * it;
                ws[c * 16 + (tkk ^ (c >> 3))] =
                    cbg[(size_t)(code0 + c) * 64 + kc * 16 + tkk];
            }
            __syncthreads();

            const float4* zsp = zs + rg * 64;    // (rg*4 + i)*16 = rg*64 + i*16
            const float4* wsp = ws + cg * 128;   // (cg*8 + j)*16 = cg*128 + j*16
            #pragma unroll 4
            for (int kk = 0; kk < 16; kk++) {
                int oz = kk ^ (rg & 15);
                int ow = kk ^ cg;
                float4 zf[4], wf[8];
                #pragma unroll
                for (int i = 0; i < 4; i++) zf[i] = zsp[i * 16 + oz];
                #pragma unroll
                for (int j = 0; j < 8; j++) wf[j] = wsp[j * 16 + ow];
                #pragma unroll
                for (int i = 0; i < 4; i++) {
                    #pragma unroll
                    for (int j = 0; j < 8; j++) {
                        float a = acc[i][j];
                        a = fmaf(zf[i].x, wf[j].x, a);
                        a = fmaf(zf[i].y, wf[j].y, a);
                        a = fmaf(zf[i].z, wf[j].z, a);
                        a = fmaf(zf[i].w, wf[j].w, a);
                        acc[i][j] = a;
                    }
                }
            }
        }

        // distances for this chunk: d = cb_sq[c] - 2*dot  (z_sq is row-constant)
        const float4* cq = (const float4*)(cbsq + code0);
        float4 q0 = cq[cg * 2];
        float4 q1 = cq[cg * 2 + 1];
        float csq[8] = { q0.x, q0.y, q0.z, q0.w, q1.x, q1.y, q1.z, q1.w };
        #pragma unroll
        for (int j = 0; j < 8; j++) {
            int c = code0 + cg * 8 + j;
            #pragma unroll
            for (int i = 0; i < 4; i++) {
                float d = fmaf(-2.0f, acc[i][j], csq[j]);
                if (d < bd[i]) { bd[i] = d; bi[i] = c; }   // codes ascend -> first-min kept
            }
        }
    }

    // reduce across the 16 lanes (cg) sharing each row group; tie -> smaller index
    #pragma unroll
    for (int m = 1; m <= 8; m <<= 1) {
        #pragma unroll
        for (int i = 0; i < 4; i++) {
            float od = __shfl_xor(bd[i], m, 64);
            int   oi = __shfl_xor(bi[i], m, 64);
            if (od < bd[i] || (od == bd[i] && oi < bi[i])) { bd[i] = od; bi[i] = oi; }
        }
    }
    if (cg == 0) {
        #pragma unroll
        for (int i = 0; i < 4; i++)
            idx_out[row0 + rg * 4 + i] = (float)bi[i];
    }
}

// -------- gather + STE + commitment partial + histogram: one wave per row --------
__global__ void gather_kernel(const float* __restrict__ z, const float* __restrict__ cb,
                              const float* __restrict__ idx_f, float* __restrict__ out,
                              int* __restrict__ usage, float* __restrict__ accum) {
    int lane = threadIdx.x & 63;
    int wid  = (blockIdx.x * blockDim.x + threadIdx.x) >> 6;   // 0..2047
    const float4* z4  = (const float4*)z;
    const float4* cb4 = (const float4*)cb;
    float4* o4 = (float4*)out;

    float local = 0.0f;
    for (int r = wid; r < NROWS; r += 2048) {
        int idx = (int)idx_f[r];
        float4 w  = cb4[(size_t)idx * 64 + lane];
        float4 zv = z4[(size_t)r * 64 + lane];
        float4 d, o;
        d.x = w.x - zv.x; d.y = w.y - zv.y; d.z = w.z - zv.z; d.w = w.w - zv.w;
        o.x = zv.x + d.x; o.y = zv.y + d.y; o.z = zv.z + d.z; o.w = zv.w + d.w;  // STE: z + (w - z)
        o4[(size_t)r * 64 + lane] = o;
        local = fmaf(d.x, d.x, local);
        local = fmaf(d.y, d.y, local);
        local = fmaf(d.z, d.z, local);
        local = fmaf(d.w, d.w, local);
        if (lane == 0) atomicAdd(&usage[idx], 1);
    }
    #pragma unroll
    for (int m = 32; m >= 1; m >>= 1) local += __shfl_xor(local, m, 64);
    if (lane == 0) atomicAdd(accum, local);
}

// -------- scalars: commitment mean + entropy loss --------
__global__ void finalize_kernel(const int* __restrict__ usage, const float* __restrict__ accum,
                                float* __restrict__ out2) {
    __shared__ float red[256];
    int t = threadIdx.x;
    float e = 0.0f;
    for (int b = t; b < NCODES; b += 256) {
        float p = (float)usage[b] * (1.0f / 65536.0f);
        e -= p * logf(p + 1e-10f);
    }
    red[t] = e;
    __syncthreads();
    if (t == 0) {
        float s = 0.0f;
        for (int k = 0; k < 256; k++) s += red[k];
        out2[0] = accum[0] / 16777216.0f;        // commitment_loss
        out2[1] = logf(2048.0f) - s;             // entropy_loss
    }
}

extern "C" void kernel_launch(void* const* d_in, const int* in_sizes, int n_in,
                              void* d_out, int out_size, void* d_ws, size_t ws_size,
                              hipStream_t stream) {
    const float* z  = (const float*)d_in[0];
    const float* cb = (const float*)d_in[1];

    float* out   = (float*)d_out;
    float* idx_f = out + (size_t)NROWS * DIM;        // 16777216
    float* out2  = idx_f + NROWS;                    // +65536

    int*   usage = (int*)d_ws;
    float* accum = (float*)((char*)d_ws + 8192);
    float* cbsq  = (float*)((char*)d_ws + 8208);

    hipMemsetAsync(d_ws, 0, 8208, stream);
    cbsq_kernel<<<512, 256, 0, stream>>>(cb, cbsq);
    argmin_kernel<<<512, 512, 0, stream>>>(z, cb, cbsq, idx_f);
    gather_kernel<<<512, 256, 0, stream>>>(z, cb, idx_f, out, usage, accum);
    finalize_kernel<<<1, 256, 0, stream>>>(usage, accum, out2);
}

// Round 2
// 374.534 us; speedup vs baseline: 3.1295x; 3.1295x over previous
//
#include <hip/hip_runtime.h>
#include <float.h>
#include <math.h>

#define NROWS 65536
#define DIM 256
#define NCODES 2048

typedef _Float16 f16x8 __attribute__((ext_vector_type(8)));
typedef float    f32x4 __attribute__((ext_vector_type(4)));

__device__ __forceinline__ void ld16(const void* g, void* l) {
    __builtin_amdgcn_global_load_lds(
        (__attribute__((address_space(1))) void*)g,
        (__attribute__((address_space(3))) void*)l, 16, 0, 0);
}

// -------- split fp32 -> (hi, lo) fp16, 8 elems/thread --------
__global__ void split_kernel(const float* __restrict__ x, _Float16* __restrict__ hi,
                             _Float16* __restrict__ lo) {
    int i = (blockIdx.x * 256 + threadIdx.x) * 8;
    float4 a = *(const float4*)(x + i);
    float4 b = *(const float4*)(x + i + 4);
    float v[8] = {a.x, a.y, a.z, a.w, b.x, b.y, b.z, b.w};
    _Float16 h[8], l[8];
    #pragma unroll
    for (int k = 0; k < 8; k++) {
        h[k] = (_Float16)v[k];
        l[k] = (_Float16)(v[k] - (float)h[k]);   // v - (float)h is exact in fp32
    }
    *(f16x8*)(hi + i) = *(const f16x8*)h;
    *(f16x8*)(lo + i) = *(const f16x8*)l;
}

// -------- codebook squared norms (fp32 exact): one wave per code --------
__global__ void cbsq_kernel(const float* __restrict__ cb, float* __restrict__ cbsq) {
    int wid  = (blockIdx.x * blockDim.x + threadIdx.x) >> 6;
    int lane = threadIdx.x & 63;
    const float4* c4 = (const float4*)cb;
    float4 v = c4[wid * 64 + lane];
    float s = v.x * v.x + v.y * v.y + v.z * v.z + v.w * v.w;
    #pragma unroll
    for (int m = 32; m >= 1; m >>= 1) s += __shfl_xor(s, m, 64);
    if (lane == 0) cbsq[wid] = s;
}

// -------- MFMA argmin: block = 128 rows x 2048 codes (8 chunks of 256) --------
// 512 blocks x 256 threads (4 waves, 2x2: wave tile 64 rows x 128 codes).
// dot = zh*wh + zh*wl + zl*wh  (fp16 split; zl*wl term ~2^-24, dropped)
__global__ __launch_bounds__(256, 2)
void argmin_kernel(const _Float16* __restrict__ zh, const _Float16* __restrict__ zl,
                   const _Float16* __restrict__ wh, const _Float16* __restrict__ wl,
                   const float* __restrict__ cbsq, float* __restrict__ idx_out) {
    __shared__ _Float16 Ah[128 * 32];   // 8 KB  (rows x k32, granule-swizzled)
    __shared__ _Float16 Al[128 * 32];   // 8 KB
    __shared__ _Float16 Bh[256 * 32];   // 16 KB (codes x k32)
    __shared__ _Float16 Bl[256 * 32];   // 16 KB
    __shared__ float rD[2][128];
    __shared__ int   rI[2][128];

    const int t    = threadIdx.x;
    const int wave = t >> 6;
    const int lane = t & 63;
    const int quad = lane >> 4;
    const int l15  = lane & 15;
    const int wr0  = (wave & 1) * 64;    // wave row offset within block tile
    const int wc0  = (wave >> 1) * 128;  // wave code offset within chunk
    const int row0 = blockIdx.x * 128;

    // swizzled read offset (granule of 8 halves): pos = quad ^ ((m>>1)&3), m-part == l15 part
    const int p8 = (quad ^ ((l15 >> 1) & 3)) * 8;

    float bd[16];
    int   bi[16];
    #pragma unroll
    for (int s = 0; s < 16; s++) { bd[s] = FLT_MAX; bi[s] = 0; }

    for (int cc = 0; cc < 8; cc++) {
        f32x4 acc[4][8];
        #pragma unroll
        for (int i = 0; i < 4; i++)
            #pragma unroll
            for (int j = 0; j < 8; j++) acc[i][j] = (f32x4){0.f, 0.f, 0.f, 0.f};

        for (int kc = 0; kc < 8; kc++) {
            __syncthreads();
            // stage A (z rows): 128x32 halves, 2 issues x 256 thr, swizzled via global addr
            #pragma unroll
            for (int it = 0; it < 2; it++) {
                int s = it * 256 + t;
                int r = s >> 2;
                int g = (s & 3) ^ ((r >> 1) & 3);
                size_t off = (size_t)(row0 + r) * 256 + kc * 32 + g * 8;
                ld16(zh + off, &Ah[s * 8]);
                ld16(zl + off, &Al[s * 8]);
            }
            // stage B (codes): 256x32 halves, 4 issues x 256 thr
            #pragma unroll
            for (int it = 0; it < 4; it++) {
                int s = it * 256 + t;
                int n = s >> 2;
                int g = (s & 3) ^ ((n >> 1) & 3);
                size_t off = (size_t)(cc * 256 + n) * 256 + kc * 32 + g * 8;
                ld16(wh + off, &Bh[s * 8]);
                ld16(wl + off, &Bl[s * 8]);
            }
            __syncthreads();

            f16x8 ah[4], al[4];
            #pragma unroll
            for (int i = 0; i < 4; i++) {
                int off = (wr0 + i * 16 + l15) * 32 + p8;
                ah[i] = *(const f16x8*)&Ah[off];
                al[i] = *(const f16x8*)&Al[off];
            }
            #pragma unroll
            for (int j = 0; j < 8; j++) {
                int offb = (wc0 + j * 16 + l15) * 32 + p8;
                f16x8 bh = *(const f16x8*)&Bh[offb];
                f16x8 bl = *(const f16x8*)&Bl[offb];
                #pragma unroll
                for (int i = 0; i < 4; i++) {
                    acc[i][j] = __builtin_amdgcn_mfma_f32_16x16x32_f16(ah[i], bh, acc[i][j], 0, 0, 0);
                    acc[i][j] = __builtin_amdgcn_mfma_f32_16x16x32_f16(ah[i], bl, acc[i][j], 0, 0, 0);
                    acc[i][j] = __builtin_amdgcn_mfma_f32_16x16x32_f16(al[i], bh, acc[i][j], 0, 0, 0);
                }
            }
        }

        // epilogue: d = cbsq[c] - 2*dot ; codes ascend (cc, then j) -> first-min kept
        #pragma unroll
        for (int j = 0; j < 8; j++) {
            int c = cc * 256 + wc0 + j * 16 + l15;
            float csq = cbsq[c];
            #pragma unroll
            for (int i = 0; i < 4; i++) {
                #pragma unroll
                for (int r = 0; r < 4; r++) {
                    float d = fmaf(-2.0f, acc[i][j][r], csq);
                    int s = i * 4 + r;
                    if (d < bd[s]) { bd[s] = d; bi[s] = c; }
                }
            }
        }
    }

    // reduce across the 16 lanes (l15) holding the same rows; tie -> smaller index
    #pragma unroll
    for (int m = 1; m <= 8; m <<= 1) {
        #pragma unroll
        for (int s = 0; s < 16; s++) {
            float od = __shfl_xor(bd[s], m, 64);
            int   oi = __shfl_xor(bi[s], m, 64);
            if (od < bd[s] || (od == bd[s] && oi < bi[s])) { bd[s] = od; bi[s] = oi; }
        }
    }
    __syncthreads();
    if (l15 == 0) {
        #pragma unroll
        for (int i = 0; i < 4; i++)
            #pragma unroll
            for (int r = 0; r < 4; r++) {
                int row = wr0 + i * 16 + quad * 4 + r;
                rD[wave >> 1][row] = bd[i * 4 + r];
                rI[wave >> 1][row] = bi[i * 4 + r];
            }
    }
    __syncthreads();
    if (t < 128) {
        float d0 = rD[0][t]; int i0 = rI[0][t];
        float d1 = rD[1][t]; int i1 = rI[1][t];
        int best = (d1 < d0 || (d1 == d0 && i1 < i0)) ? i1 : i0;
        idx_out[row0 + t] = (float)best;
    }
}

// -------- gather + STE + commitment partial + histogram: one wave per row --------
__global__ void gather_kernel(const float* __restrict__ z, const float* __restrict__ cb,
                              const float* __restrict__ idx_f, float* __restrict__ out,
                              int* __restrict__ usage, float* __restrict__ accum) {
    int lane = threadIdx.x & 63;
    int wid  = (blockIdx.x * blockDim.x + threadIdx.x) >> 6;
    const float4* z4  = (const float4*)z;
    const float4* cb4 = (const float4*)cb;
    float4* o4 = (float4*)out;

    float local = 0.0f;
    for (int r = wid; r < NROWS; r += 2048) {
        int idx = (int)idx_f[r];
        float4 w  = cb4[(size_t)idx * 64 + lane];
        float4 zv = z4[(size_t)r * 64 + lane];
        float4 d, o;
        d.x = w.x - zv.x; d.y = w.y - zv.y; d.z = w.z - zv.z; d.w = w.w - zv.w;
        o.x = zv.x + d.x; o.y = zv.y + d.y; o.z = zv.z + d.z; o.w = zv.w + d.w;
        o4[(size_t)r * 64 + lane] = o;
        local = fmaf(d.x, d.x, local);
        local = fmaf(d.y, d.y, local);
        local = fmaf(d.z, d.z, local);
        local = fmaf(d.w, d.w, local);
        if (lane == 0) atomicAdd(&usage[idx], 1);
    }
    #pragma unroll
    for (int m = 32; m >= 1; m >>= 1) local += __shfl_xor(local, m, 64);
    if (lane == 0) atomicAdd(accum, local);
}

// -------- scalars: commitment mean + entropy loss --------
__global__ void finalize_kernel(const int* __restrict__ usage, const float* __restrict__ accum,
                                float* __restrict__ out2) {
    __shared__ float red[256];
    int t = threadIdx.x;
    float e = 0.0f;
    for (int b = t; b < NCODES; b += 256) {
        float p = (float)usage[b] * (1.0f / 65536.0f);
        e -= p * logf(p + 1e-10f);
    }
    red[t] = e;
    __syncthreads();
    if (t == 0) {
        float s = 0.0f;
        for (int k = 0; k < 256; k++) s += red[k];
        out2[0] = accum[0] / 16777216.0f;
        out2[1] = logf(2048.0f) - s;
    }
}

extern "C" void kernel_launch(void* const* d_in, const int* in_sizes, int n_in,
                              void* d_out, int out_size, void* d_ws, size_t ws_size,
                              hipStream_t stream) {
    const float* z  = (const float*)d_in[0];
    const float* cb = (const float*)d_in[1];

    float* out   = (float*)d_out;
    float* idx_f = out + (size_t)NROWS * DIM;   // float offset 16777216 (byte 67108864)
    float* out2  = idx_f + NROWS;

    // z hi/lo scratch lives in the zq output region (exactly 64 MB), overwritten
    // later by gather_kernel. 0..33554432: zh ; 33554432..67108864: zl.
    _Float16* zh = (_Float16*)d_out;
    _Float16* zl = zh + (size_t)NROWS * DIM;

    // ws: wh 1MB | wl 1MB | cbsq 8KB | usage 8KB | accum 4B
    _Float16* wh   = (_Float16*)d_ws;
    _Float16* wl   = wh + (size_t)NCODES * DIM;
    float*    cbsq = (float*)((char*)d_ws + 2097152);
    int*      usage= (int*)((char*)d_ws + 2105344);
    float*    accum= (float*)((char*)d_ws + 2113536);

    hipMemsetAsync((char*)d_ws + 2105344, 0, 8196, stream);
    split_kernel<<<8192, 256, 0, stream>>>(z, zh, zl);     // 16.78M elems
    split_kernel<<<256, 256, 0, stream>>>(cb, wh, wl);     // 524288 elems
    cbsq_kernel<<<512, 256, 0, stream>>>(cb, cbsq);
    argmin_kernel<<<512, 256, 0, stream>>>(zh, zl, wh, wl, cbsq, idx_f);
    gather_kernel<<<512, 256, 0, stream>>>(z, cb, idx_f, out, usage, accum);
    finalize_kernel<<<1, 256, 0, stream>>>(usage, accum, out2);
}